// Round 13
// baseline (891.568 us; speedup 1.0000x reference)
//
#include <hip/hip_runtime.h>
#include <hip/hip_bf16.h>

#define N_NODES 16384
#define FDIM 512

typedef __attribute__((address_space(1))) const void gvoid_t;
typedef __attribute__((address_space(3))) void lvoid_t;
typedef float vfloat4 __attribute__((ext_vector_type(4)));

#define SCHED_FENCE() __builtin_amdgcn_sched_barrier(0)

// ---------------- barrier-free A-pass: out = epilogue(A @ V + bias) ----------------
// The r6-r12 A-passes were all barrier-locked (LDS V-staging forces block-wide
// s_barrier every tile; vmcnt couples A-prefetch to stage schedule). This kernel
// removes LDS entirely: lane l owns k = l (mod 64); per 64-k step it loads
// A[r][k] via coalesced 256 B/instr dword nt-loads and V[k][0..15] as four
// contiguous dwordx4 (64 B/lane; 4 KB V-window shared by the block's waves via
// L1; V fully L2-resident). No barriers -> waves free-run; 2-step software
// pipeline gives unconstrained A-prefetch depth. acc 64 + a/v dbuf 40 + addr
// ~116 VGPR -> 128 tier (launch_bounds(256,2) pins it), 16 waves/CU, LDS 0.
template <int RELU, int HASBIAS, int FUSE>
__global__ __launch_bounds__(256, 2)
void k_bcast(const float* __restrict__ A,
             const float* __restrict__ V,
             const float* __restrict__ bias,
             float* __restrict__ out,
             const float* __restrict__ w2,
             const float* __restrict__ wd,
             const float* __restrict__ bdp) {
    const int tid = threadIdx.x;
    const int lane = tid & 63;
    const int w = tid >> 6;
    const size_t row0 = (size_t)blockIdx.x * 16 + (size_t)w * 4;

    float acc[4][16];
#pragma unroll
    for (int r = 0; r < 4; ++r)
#pragma unroll
        for (int c = 0; c < 16; ++c) acc[r][c] = 0.f;

    auto LOADS = [&](int step, float (&a)[4], vfloat4 (&v)[4]) {
        const size_t kk = (size_t)step * 64 + lane;
#pragma unroll
        for (int r = 0; r < 4; ++r)
            a[r] = __builtin_nontemporal_load(A + (row0 + r) * (size_t)N_NODES + kk);
#pragma unroll
        for (int cc = 0; cc < 4; ++cc)
            v[cc] = *reinterpret_cast<const vfloat4*>(V + kk * 16 + cc * 4);
    };

    auto FMAS = [&](const float (&a)[4], const vfloat4 (&v)[4]) {
#pragma unroll
        for (int cc = 0; cc < 4; ++cc) {
#pragma unroll
            for (int r = 0; r < 4; ++r) {
                acc[r][cc * 4 + 0] += a[r] * v[cc][0];
                acc[r][cc * 4 + 1] += a[r] * v[cc][1];
                acc[r][cc * 4 + 2] += a[r] * v[cc][2];
                acc[r][cc * 4 + 3] += a[r] * v[cc][3];
            }
        }
    };

    float aX[4], aY[4];
    vfloat4 vX[4], vY[4];

    LOADS(0, aX, vX);
#pragma unroll 1
    for (int s = 0; s < N_NODES / 64; s += 2) {
        LOADS(s + 1, aY, vY);
        FMAS(aX, vX);
        if (s + 2 < N_NODES / 64) LOADS(s + 2, aX, vX);
        FMAS(aY, vY);
    }

    // butterfly-reduce the 64 (r,c) partials; lane v=r*16+c keeps value v.
    float o = 0.f;
#pragma unroll
    for (int r = 0; r < 4; ++r) {
#pragma unroll
        for (int c = 0; c < 16; ++c) {
            float s = acc[r][c];
            s += __shfl_xor(s, 1);  s += __shfl_xor(s, 2);  s += __shfl_xor(s, 4);
            s += __shfl_xor(s, 8);  s += __shfl_xor(s, 16); s += __shfl_xor(s, 32);
            o = (r * 16 + c == lane) ? s : o;
        }
    }
    if (HASBIAS) o += bias[lane & 15];
    if (RELU) o = fmaxf(o, 0.f);

    if (FUSE == 0) {
        out[row0 * 16 + lane] = o;
    } else if (FUSE == 1) {
        // hw[row][c] = sum_k h[row][k]*W2[k][c]; h[row][k] in lane (lane&48)|k
        const int c = lane & 15;
        float s = 0.f;
#pragma unroll
        for (int k = 0; k < 16; ++k) {
            const float hk = __shfl(o, (lane & 48) + k);
            s += hk * w2[k * 16 + c];
        }
        out[row0 * 16 + lane] = s;
    } else {
        // softmax over the 16-lane class group, dot Wd, + bd -> scalar per row
        const int c = lane & 15;
        float m = o;
        m = fmaxf(m, __shfl_xor(m, 1));
        m = fmaxf(m, __shfl_xor(m, 2));
        m = fmaxf(m, __shfl_xor(m, 4));
        m = fmaxf(m, __shfl_xor(m, 8));
        const float e = expf(o - m);
        float se = e, sd = e * wd[c];
        se += __shfl_xor(se, 1); sd += __shfl_xor(sd, 1);
        se += __shfl_xor(se, 2); sd += __shfl_xor(sd, 2);
        se += __shfl_xor(se, 4); sd += __shfl_xor(sd, 4);
        se += __shfl_xor(se, 8); sd += __shfl_xor(sd, 8);
        if (c == 0) out[row0 + (lane >> 4)] = sd / se + bdp[0];
    }
}

// ---------------- k1 = x @ W1 (r11 LDS-pipelined kernel, unchanged) ----------------
template <int KTOT, int RELU, int HASBIAS>
__global__ __launch_bounds__(256, 2)
void k_rowagg(const float* __restrict__ A,
              const float* __restrict__ V,
              const float* __restrict__ bias,
              float* __restrict__ out) {
    constexpr int KT = 256;
    constexpr int NT = KTOT / KT;
    constexpr int TB = KT * 16 * 4;
    __shared__ char lv[2 * TB];

    const int tid = threadIdx.x;
    const int lane = tid & 63;
    const int w = tid >> 6;
    const size_t row0 = (size_t)blockIdx.x * 16 + (size_t)w * 4;

    int sw_src[4];
#pragma unroll
    for (int s = 0; s < 4; ++s) {
        const int D = s * 4096 + tid * 16;
        sw_src[s] = (D ^ (((D >> 8) & 7) << 4)) >> 2;
    }

    unsigned zoff = 0;

    auto STAGE = [&](int halfoff, int t) {
        const float* vt = V + (size_t)t * (KT * 16);
#pragma unroll
        for (int s = 0; s < 4; ++s) {
            __builtin_amdgcn_global_load_lds(
                (gvoid_t*)(const void*)(vt + sw_src[s]),
                (lvoid_t*)(void*)(lv + zoff + halfoff + s * 4096 + tid * 16),
                16, 0, 0);
        }
    };

    auto LOADA = [&](vfloat4 (&a)[4], int t) {
#pragma unroll
        for (int r = 0; r < 4; ++r)
            a[r] = __builtin_nontemporal_load(
                reinterpret_cast<const vfloat4*>(
                    A + (row0 + r) * (size_t)KTOT + (size_t)t * KT + lane * 4));
    };

    float acc[4][16];
#pragma unroll
    for (int r = 0; r < 4; ++r)
#pragma unroll
        for (int c = 0; c < 16; ++c) acc[r][c] = 0.f;

    auto COMPUTE = [&](const vfloat4 (&a)[4], unsigned roff) {
#pragma unroll
        for (int kk = 0; kk < 4; ++kk) {
            vfloat4 vv[4];
#pragma unroll
            for (int cc = 0; cc < 4; ++cc) {
                const unsigned B = (unsigned)lane * 256u + ((unsigned)kk << 6) +
                                   ((unsigned)cc << 4);
                const unsigned P = B ^ (((unsigned)lane & 7u) << 4);
                vv[cc] = *reinterpret_cast<const vfloat4*>(lv + roff + P);
            }
#pragma unroll
            for (int cc = 0; cc < 4; ++cc) {
#pragma unroll
                for (int r = 0; r < 4; ++r) {
                    const float ak = a[r][kk];
                    acc[r][cc * 4 + 0] += ak * vv[cc][0];
                    acc[r][cc * 4 + 1] += ak * vv[cc][1];
                    acc[r][cc * 4 + 2] += ak * vv[cc][2];
                    acc[r][cc * 4 + 3] += ak * vv[cc][3];
                }
            }
        }
    };

    vfloat4 a0[4], a1[4];

    STAGE(0, 0);
    SCHED_FENCE();
    LOADA(a0, 0);
    SCHED_FENCE();
    asm volatile("s_waitcnt vmcnt(4)" ::: "memory");
    __builtin_amdgcn_s_barrier();
    asm volatile("" : "+v"(zoff));
    SCHED_FENCE();

#pragma unroll 1
    for (int t = 0; t < NT; t += 2) {
        STAGE(TB, t + 1);
        SCHED_FENCE();
        LOADA(a1, t + 1);
        SCHED_FENCE();
        COMPUTE(a0, zoff + 0);
        SCHED_FENCE();
        asm volatile("s_waitcnt vmcnt(4)" ::: "memory");
        __builtin_amdgcn_s_barrier();
        asm volatile("" : "+v"(zoff));
        SCHED_FENCE();

        if (t + 2 < NT) {
            STAGE(0, t + 2);
            SCHED_FENCE();
            LOADA(a0, t + 2);
            SCHED_FENCE();
            COMPUTE(a1, zoff + TB);
            SCHED_FENCE();
            asm volatile("s_waitcnt vmcnt(4)" ::: "memory");
            __builtin_amdgcn_s_barrier();
            asm volatile("" : "+v"(zoff));
            SCHED_FENCE();
        } else {
            COMPUTE(a1, zoff + TB);
        }
    }

    float o = 0.f;
#pragma unroll
    for (int r = 0; r < 4; ++r) {
#pragma unroll
        for (int c = 0; c < 16; ++c) {
            float s = acc[r][c];
            s += __shfl_xor(s, 1);  s += __shfl_xor(s, 2);  s += __shfl_xor(s, 4);
            s += __shfl_xor(s, 8);  s += __shfl_xor(s, 16); s += __shfl_xor(s, 32);
            o = (r * 16 + c == lane) ? s : o;
        }
    }
    if (HASBIAS) o += bias[lane & 15];
    if (RELU) o = fmaxf(o, 0.f);
    out[row0 * 16 + lane] = o;
}

extern "C" void kernel_launch(void* const* d_in, const int* in_sizes, int n_in,
                              void* d_out, int out_size, void* d_ws, size_t ws_size,
                              hipStream_t stream) {
    const float* x  = (const float*)d_in[0];
    const float* A  = (const float*)d_in[1];
    const float* W1 = (const float*)d_in[2];
    const float* b1 = (const float*)d_in[3];
    const float* W2 = (const float*)d_in[4];
    const float* b2 = (const float*)d_in[5];
    const float* Wd = (const float*)d_in[6];
    const float* bd = (const float*)d_in[7];
    float* out = (float*)d_out;

    float* ws = (float*)d_ws;
    float* xw = ws;                        // [N,16] 1 MB
    float* hw = ws + 1 * N_NODES * 16;     // [N,16] 1 MB

    // xw = x @ W1   (LDS-pipelined kernel, KTOT=512)
    k_rowagg<FDIM, 0, 0><<<N_NODES / 16, 256, 0, stream>>>(x, W1, b1, xw);
    // hw = relu(A @ xw + b1) @ W2    (barrier-free pass 1, fused k3)
    k_bcast<1, 1, 1><<<N_NODES / 16, 256, 0, stream>>>(
        A, xw, b1, hw, W2, nullptr, nullptr);
    // out = softmax(A @ hw + b2) @ Wd + bd    (barrier-free pass 2, fused k5)
    k_bcast<0, 1, 2><<<N_NODES / 16, 256, 0, stream>>>(
        A, hw, b2, out, nullptr, Wd, bd);
}

// Round 14
// 453.062 us; speedup vs baseline: 1.9679x; 1.9679x over previous
//
#include <hip/hip_runtime.h>
#include <hip/hip_bf16.h>

#define N_NODES 16384
#define FDIM 512

typedef __attribute__((address_space(1))) const void gvoid_t;
typedef __attribute__((address_space(3))) void lvoid_t;
typedef float vfloat4 __attribute__((ext_vector_type(4)));

#define SCHED_FENCE() __builtin_amdgcn_sched_barrier(0)

// ---------------- pipelined row-aggregation GEMM (r11, the proven optimum) ----------------
// 4 waves/block, 4 rows/wave (RPW=4 = LDS floor: tile-read/wave fixed at 16 KB,
// RPW<4 goes LDS-bound — r7/r10), KT=256 double-buffered LDS (32 KB -> 4
// blocks/CU, 16 waves/CU), glds w16 staging (linear dest + pre-swizzled src),
// XOR-swizzled [k][c] tile, counted vmcnt(4) + raw s_barrier (A-prefetch in
// flight across barriers), nt A-loads (+8%: skips L2/IC allocation for the
// 1.07 GB zero-reuse A stream). Fused epilogues: FUSE=0 plain (k1), FUSE=1
// @W2 via 16 shfl+FMA (kills k3), FUSE=2 softmax.Wd+bd (kills k5).
// Residual vs 6.4 TB/s fill ceiling = DRAM read-pattern floor (16K concurrent
// 1 KB-granule row streams); all alternatives tested r7-r13 regressed or flat.
template <int KTOT, int RELU, int HASBIAS, int FUSE>
__global__ __launch_bounds__(256, 2)
void k_rowagg(const float* __restrict__ A,
              const float* __restrict__ V,
              const float* __restrict__ bias,
              float* __restrict__ out,
              const float* __restrict__ w2,
              const float* __restrict__ wd,
              const float* __restrict__ bdp) {
    constexpr int KT = 256;
    constexpr int NT = KTOT / KT;
    constexpr int TB = KT * 16 * 4;
    __shared__ char lv[2 * TB];

    const int tid = threadIdx.x;
    const int lane = tid & 63;
    const int w = tid >> 6;
    const size_t row0 = (size_t)blockIdx.x * 16 + (size_t)w * 4;

    int sw_src[4];
#pragma unroll
    for (int s = 0; s < 4; ++s) {
        const int D = s * 4096 + tid * 16;
        sw_src[s] = (D ^ (((D >> 8) & 7) << 4)) >> 2;
    }

    unsigned zoff = 0;

    auto STAGE = [&](int halfoff, int t) {
        const float* vt = V + (size_t)t * (KT * 16);
#pragma unroll
        for (int s = 0; s < 4; ++s) {
            __builtin_amdgcn_global_load_lds(
                (gvoid_t*)(const void*)(vt + sw_src[s]),
                (lvoid_t*)(void*)(lv + zoff + halfoff + s * 4096 + tid * 16),
                16, 0, 0);
        }
    };

    auto LOADA = [&](vfloat4 (&a)[4], int t) {
#pragma unroll
        for (int r = 0; r < 4; ++r)
            a[r] = __builtin_nontemporal_load(
                reinterpret_cast<const vfloat4*>(
                    A + (row0 + r) * (size_t)KTOT + (size_t)t * KT + lane * 4));
    };

    float acc[4][16];
#pragma unroll
    for (int r = 0; r < 4; ++r)
#pragma unroll
        for (int c = 0; c < 16; ++c) acc[r][c] = 0.f;

    auto COMPUTE = [&](const vfloat4 (&a)[4], unsigned roff) {
#pragma unroll
        for (int kk = 0; kk < 4; ++kk) {
            vfloat4 vv[4];
#pragma unroll
            for (int cc = 0; cc < 4; ++cc) {
                const unsigned B = (unsigned)lane * 256u + ((unsigned)kk << 6) +
                                   ((unsigned)cc << 4);
                const unsigned P = B ^ (((unsigned)lane & 7u) << 4);
                vv[cc] = *reinterpret_cast<const vfloat4*>(lv + roff + P);
            }
#pragma unroll
            for (int cc = 0; cc < 4; ++cc) {
#pragma unroll
                for (int r = 0; r < 4; ++r) {
                    const float ak = a[r][kk];
                    acc[r][cc * 4 + 0] += ak * vv[cc][0];
                    acc[r][cc * 4 + 1] += ak * vv[cc][1];
                    acc[r][cc * 4 + 2] += ak * vv[cc][2];
                    acc[r][cc * 4 + 3] += ak * vv[cc][3];
                }
            }
        }
    };

    vfloat4 a0[4], a1[4];

    STAGE(0, 0);
    SCHED_FENCE();
    LOADA(a0, 0);
    SCHED_FENCE();
    asm volatile("s_waitcnt vmcnt(4)" ::: "memory");
    __builtin_amdgcn_s_barrier();
    asm volatile("" : "+v"(zoff));
    SCHED_FENCE();

#pragma unroll 1
    for (int t = 0; t < NT; t += 2) {
        STAGE(TB, t + 1);
        SCHED_FENCE();
        LOADA(a1, t + 1);
        SCHED_FENCE();
        COMPUTE(a0, zoff + 0);
        SCHED_FENCE();
        asm volatile("s_waitcnt vmcnt(4)" ::: "memory");
        __builtin_amdgcn_s_barrier();
        asm volatile("" : "+v"(zoff));
        SCHED_FENCE();

        if (t + 2 < NT) {
            STAGE(0, t + 2);
            SCHED_FENCE();
            LOADA(a0, t + 2);
            SCHED_FENCE();
            COMPUTE(a1, zoff + TB);
            SCHED_FENCE();
            asm volatile("s_waitcnt vmcnt(4)" ::: "memory");
            __builtin_amdgcn_s_barrier();
            asm volatile("" : "+v"(zoff));
            SCHED_FENCE();
        } else {
            COMPUTE(a1, zoff + TB);
        }
    }

    // butterfly-reduce the 64 (r,c) partials; lane v=r*16+c keeps value v.
    float o = 0.f;
#pragma unroll
    for (int r = 0; r < 4; ++r) {
#pragma unroll
        for (int c = 0; c < 16; ++c) {
            float s = acc[r][c];
            s += __shfl_xor(s, 1);  s += __shfl_xor(s, 2);  s += __shfl_xor(s, 4);
            s += __shfl_xor(s, 8);  s += __shfl_xor(s, 16); s += __shfl_xor(s, 32);
            o = (r * 16 + c == lane) ? s : o;
        }
    }
    if (HASBIAS) o += bias[lane & 15];
    if (RELU) o = fmaxf(o, 0.f);

    if (FUSE == 0) {
        out[row0 * 16 + lane] = o;
    } else if (FUSE == 1) {
        // hw[row][c] = sum_k h[row][k] * W2[k][c]; h[row][k] in lane (lane&48)|k
        const int c = lane & 15;
        float s = 0.f;
#pragma unroll
        for (int k = 0; k < 16; ++k) {
            const float hk = __shfl(o, (lane & 48) + k);
            s += hk * w2[k * 16 + c];
        }
        out[row0 * 16 + lane] = s;
    } else {
        // softmax over the 16-lane class group, dot Wd, + bd -> scalar per row
        const int c = lane & 15;
        float m = o;
        m = fmaxf(m, __shfl_xor(m, 1));
        m = fmaxf(m, __shfl_xor(m, 2));
        m = fmaxf(m, __shfl_xor(m, 4));
        m = fmaxf(m, __shfl_xor(m, 8));
        const float e = expf(o - m);
        float se = e, sd = e * wd[c];
        se += __shfl_xor(se, 1); sd += __shfl_xor(sd, 1);
        se += __shfl_xor(se, 2); sd += __shfl_xor(sd, 2);
        se += __shfl_xor(se, 4); sd += __shfl_xor(sd, 4);
        se += __shfl_xor(se, 8); sd += __shfl_xor(sd, 8);
        if (c == 0) out[row0 + (lane >> 4)] = sd / se + bdp[0];
    }
}

extern "C" void kernel_launch(void* const* d_in, const int* in_sizes, int n_in,
                              void* d_out, int out_size, void* d_ws, size_t ws_size,
                              hipStream_t stream) {
    const float* x  = (const float*)d_in[0];
    const float* A  = (const float*)d_in[1];
    const float* W1 = (const float*)d_in[2];
    const float* b1 = (const float*)d_in[3];
    const float* W2 = (const float*)d_in[4];
    const float* b2 = (const float*)d_in[5];
    const float* Wd = (const float*)d_in[6];
    const float* bd = (const float*)d_in[7];
    float* out = (float*)d_out;

    float* ws = (float*)d_ws;
    float* xw = ws;                        // [N,16] 1 MB
    float* hw = ws + 1 * N_NODES * 16;     // [N,16] 1 MB

    // xw = x @ W1
    k_rowagg<FDIM, 0, 0, 0><<<N_NODES / 16, 256, 0, stream>>>(
        x, W1, b1, xw, nullptr, nullptr, nullptr);
    // hw = relu(A @ xw + b1) @ W2    (pass 1, fused k3)
    k_rowagg<N_NODES, 1, 1, 1><<<N_NODES / 16, 256, 0, stream>>>(
        A, xw, b1, hw, W2, nullptr, nullptr);
    // out = softmax(A @ hw + b2) @ Wd + bd    (pass 2, fused k5)
    k_rowagg<N_NODES, 0, 1, 2><<<N_NODES / 16, 256, 0, stream>>>(
        A, hw, b2, out, nullptr, Wd, bd);
}